// Round 12
// baseline (4698.759 us; speedup 1.0000x reference)
//
#include <hip/hip_runtime.h>

#define TT   128
#define FF   64
#define HH   512
#define GG   2048    // 4H
#define K1   576
#define K2   1024
#define KB1  72      // K1/8
#define KB2  128     // K2/8
#define NBLK 256
#define QS   520     // Q row stride in halves (1040B, 16B-aligned)

using f16x8 = __attribute__((ext_vector_type(8))) _Float16;
using f16x4 = __attribute__((ext_vector_type(4))) _Float16;
using f16x2 = __attribute__((ext_vector_type(2))) _Float16;
using f32x4 = __attribute__((ext_vector_type(4))) float;

// ---------------------------------------------------------------------------
// Coalesced repack (validated r9-r11): block kb stages 8 rows of [U;W] into
// LDS, writes dest-linear 16B chunks. Layout: element (ct,kb,c,j) at
// ((ct*K8+kb)*16+c)*8+j holds B[k=kb*8+j][col], col=(c&3)*512+ct*4+(c>>2).
// ---------------------------------------------------------------------------
__global__ void pack_weights(const float* __restrict__ U, const float* __restrict__ W,
                             const float* __restrict__ bias, int K8, int Kh,
                             _Float16* __restrict__ Bp, float* __restrict__ pb)
{
    __shared__ _Float16 T[8][GG];
    const int kb = blockIdx.x;
    const int tid = threadIdx.x;
    for (int i = tid; i < 8 * (GG / 4); i += 256) {
        int r = i / (GG / 4), c4 = (i % (GG / 4)) * 4;
        int k = kb * 8 + r;
        const float* src = (k < Kh) ? (U + (size_t)k * GG) : (W + (size_t)(k - Kh) * GG);
        float4 v = *(const float4*)(src + c4);
        T[r][c4 + 0] = (_Float16)v.x; T[r][c4 + 1] = (_Float16)v.y;
        T[r][c4 + 2] = (_Float16)v.z; T[r][c4 + 3] = (_Float16)v.w;
    }
    __syncthreads();
    for (int m = tid; m < 2048; m += 256) {
        int ct = m >> 4, c = m & 15;
        int col = (c & 3) * HH + ct * 4 + (c >> 2);
        f16x8 v;
#pragma unroll
        for (int j = 0; j < 8; ++j) v[j] = T[j][col];
        *(f16x8*)(Bp + (((size_t)ct * K8 + kb) * 16 + c) * 8) = v;
    }
    if (kb == 0)
        for (int p = tid; p < GG; p += 256) {
            int ct = p >> 4, c = p & 15;
            pb[p] = bias[(c & 3) * HH + ct * 4 + (c >> 2)];
        }
}

// DPP quad_perm broadcast (VALU). Validated r3-r11.
template <int CTRL>
__device__ __forceinline__ float qbcast(float v) {
    return __int_as_float(__builtin_amdgcn_mov_dpp(__float_as_int(v), CTRL, 0xF, 0xF, true));
}

// async global->LDS DMA, 16B/lane, sc0 (L1-bypass; L2 is coherence point). r9.
__device__ __forceinline__ void gld_lds16_sc0(const _Float16* g, _Float16* l) {
    __builtin_amdgcn_global_load_lds(
        (__attribute__((address_space(1))) const void*)g,
        (__attribute__((address_space(3))) void*)l, 16, 0, 1);
}

// ---------------------------------------------------------------------------
// Gate epilogue, single-activation form (validated r10/r11): each lane
// activates its own gate, then quad-broadcasts the activated value.
// C/D 16x16: col=lane&15, row=kq*4+j. cs stride 33, hst stride 40.
// ---------------------------------------------------------------------------
__device__ __forceinline__ void lstm_epi(
    f32x4 v4, float bias, float* __restrict__ cs, _Float16* __restrict__ hstp,
    int R0, int kq, int c, int ubase)
{
    const int gsel = c & 3;
    const int ub = ubase + (c >> 2);
#pragma unroll
    for (int j = 0; j < 4; ++j) {
        float v = v4[j] + bias;
        float sig = 1.f / (1.f + __expf(-v));
        float act = (gsel == 2) ? (v > 0.f ? v : 0.f) : sig;
        float ig  = qbcast<0x00>(act);
        float fg  = qbcast<0x55>(act);
        float cin = qbcast<0xAA>(act);
        float og  = qbcast<0xFF>(act);
        int Rl = kq * 4 + j;
        int R = R0 + Rl;
        float cp = cs[R * 33 + ub];
        float cn = fg * cp + ig * cin;
        float hn = og * (cn > 0.f ? cn : 0.f);
        if (gsel == 0) {
            cs[R * 33 + ub] = cn;
            hstp[Rl * 40 + ub] = (_Float16)hn;
        }
    }
}

#define MFMA16(av, bv, acc) \
    acc = __builtin_amdgcn_mfma_f32_16x16x32_f16(av, bv, acc, 0, 0, 0)

// ---------------------------------------------------------------------------
// Persistent 2-layer LSTM. 256 blocks (1/CU) x 512 threads (8 waves,
// 2 waves/SIMD). r12: SPLIT-K WAVE PAIRS at 8 waves — wave (p=w&3, kh=w>>2)
// owns 2 tiles (32 cols) x half-K = 200 regs (AGPR-pinned), so each ds_read
// feeds 2 MFMAs and per-wave A-reads halve vs r11 (400->200 b128/chunk/CU).
// L1 K-split 288|288 (kh1 takes x tail); L2 split = h2|h1 exactly.
// Pipelined regions (1 barrier each), partials cross the barrier via
// parity-buffered xb (r10-validated):
//   region ch: DMA(ch+1) || hstore(ch-2) || epi(ch-1) || partials(ch)
// XCD-local rg mapping (r8), relaxed rowgroup barrier (r9), sc0 DMA (r9).
// ---------------------------------------------------------------------------
__global__ __launch_bounds__(512, 2) void lstm_persist(
    const float* __restrict__ x,
    const _Float16* __restrict__ Bp1, const float* __restrict__ pb1,
    const _Float16* __restrict__ Bp2, const float* __restrict__ pb2,
    const float* __restrict__ Wd, const float* __restrict__ bd,
    _Float16* __restrict__ h1b,   // [2][2048][512]
    _Float16* __restrict__ h2b,   // [2][2048][512]
    unsigned* __restrict__ bar,   // [16][32] rowgroup counters
    float* __restrict__ out)
{
    __shared__ _Float16 Q1[2][16 * QS];      // 32.5KB h1 chunks
    __shared__ _Float16 Q2[2][16 * QS];      // 32.5KB h2 chunks
    __shared__ _Float16 Xp[2][16][72];       // 4.5KB  x_t fp16
    __shared__ float    c1s[128 * 33];       // 16.5KB
    __shared__ float    c2s[128 * 33];       // 16.5KB
    __shared__ _Float16 hst[2][2][16][40];   // 5KB   [parity][layer][row][unit]
    __shared__ float    xb[2][2][4][2][256]; // 32KB  [par][layer][p][src_kh][lane*4]

    const int tid = threadIdx.x;
    const int w = tid >> 6, lane = tid & 63;
    const int p = w & 3, kh = w >> 2;
    const int b = blockIdx.x;
    const int rg = 2 * (b & 7) + ((b >> 3) & 1);   // XCD-local rowgroup
    const int cg = b >> 4;
    const int r0 = rg * 128;
    const int c = lane & 15, kq = lane >> 4;

    for (int i = tid; i < 128 * 33; i += 512) { c1s[i] = 0.f; c2s[i] = 0.f; }
    for (int i = tid; i < 2 * 2 * 16 * 40; i += 512) (&hst[0][0][0][0])[i] = (_Float16)0.f;

    // ---- one-time: 2 tiles x half-K -> 200 regs, AGPR-pinned ----
    const int ct0 = cg * 8 + 2 * p;
    f16x8 w1f[2][9], w2f[2][16];
#pragma unroll
    for (int ti = 0; ti < 2; ++ti) {
#pragma unroll
        for (int kc = 0; kc < 9; ++kc)
            w1f[ti][kc] = *(const f16x8*)(Bp1 +
                (((size_t)(ct0 + ti) * KB1 + (kh * 9 + kc) * 4 + kq) * 16 + c) * 8);
#pragma unroll
        for (int kc = 0; kc < 16; ++kc)
            w2f[ti][kc] = *(const f16x8*)(Bp2 +
                (((size_t)(ct0 + ti) * KB2 + (kh * 16 + kc) * 4 + kq) * 16 + c) * 8);
    }
#pragma unroll
    for (int ti = 0; ti < 2; ++ti) {
#pragma unroll
        for (int kc = 0; kc < 9; ++kc) asm volatile("" : "+a"(w1f[ti][kc]));
#pragma unroll
        for (int kc = 0; kc < 16; ++kc) asm volatile("" : "+a"(w2f[ti][kc]));
    }

    // own (epilogued) tile = ct0 + kh; units (2p+kh)*4..+3
    const float bias1 = pb1[(ct0 + kh) * 16 + c];
    const float bias2 = pb2[(ct0 + kh) * 16 + c];
    const int ub0 = (2 * p + kh) * 4;

    const int xrow = tid >> 5, xc2 = (tid & 31) * 2;

    for (int s = 0; s <= TT; ++s) {
        const int pr1 = (s + 1) & 1, pw1 = s & 1;
        const int pr2 = s & 1,       pw2 = (s + 1) & 1;
        const _Float16* h1r = h1b + (size_t)pr1 * 2048 * HH;
        const _Float16* h2r = h2b + (size_t)pr2 * 2048 * HH;
        _Float16* h1w = h1b + (size_t)pw1 * 2048 * HH;
        _Float16* h2w = h2b + (size_t)pw2 * 2048 * HH;
        const bool notLast = (s < TT);

        // ---- prologue: stage chunk 0 (DMA sc0) + x(0) ----
        {
#pragma unroll
            for (int i = 0; i < 2; ++i) {
                int r = w * 2 + i;
                gld_lds16_sc0(h1r + (size_t)(r0 + r) * HH + lane * 8, &Q1[0][r * QS]);
                gld_lds16_sc0(h2r + (size_t)(r0 + r) * HH + lane * 8, &Q2[0][r * QS]);
            }
            if (notLast) {
                float2 xv = *(const float2*)(x + ((size_t)(r0 + xrow) * TT + s) * FF + xc2);
                *(f16x2*)&Xp[0][xrow][xc2] = (f16x2){(_Float16)xv.x, (_Float16)xv.y};
            }
        }
        __syncthreads();

        f32x4 ownA{0.f, 0.f, 0.f, 0.f}, ownB = ownA;

        // ---- pipelined regions ch=0..8 + tail; 1 barrier each ----
        for (int ch = 0; ch <= 8; ++ch) {
            const int par = ch & 1;

            // (1) DMA prefetch chunk ch+1 -> Q[par^1]
            if (ch <= 6) {
                const int gr = r0 + (ch + 1) * 16;
#pragma unroll
                for (int i = 0; i < 2; ++i) {
                    int r = w * 2 + i;
                    gld_lds16_sc0(h1r + (size_t)(gr + r) * HH + lane * 8, &Q1[par ^ 1][r * QS]);
                    gld_lds16_sc0(h2r + (size_t)(gr + r) * HH + lane * 8, &Q2[par ^ 1][r * QS]);
                }
            }
            float2 xnext{0.f, 0.f};
            const bool havex = (ch <= 6) && notLast;
            if (havex)
                xnext = *(const float2*)(x +
                    ((size_t)(r0 + (ch + 1) * 16 + xrow) * TT + s) * FF + xc2);

            // (2) hstore chunk ch-2 from hst[par] (256 threads, f16x4)
            if (ch >= 2 && tid < 256) {
                int layer = tid >> 7, r = (tid >> 3) & 15, cq = tid & 7;
                f16x4 hv = *(const f16x4*)&hst[par][layer][r][cq * 4];
                _Float16* dst = (layer ? h2w : h1w)
                    + (size_t)(r0 + (ch - 2) * 16 + r) * HH + cg * 32 + cq * 4;
                *(f16x4*)dst = hv;
            }

            // (3) combine + epilogue chunk ch-1: own partial + partner's (xb[par^1])
            if (ch >= 1) {
                const int R0 = (ch - 1) * 16;
                if (notLast) {
                    f32x4 f = ownA + *(const f32x4*)&xb[par ^ 1][0][p][kh ^ 1][lane * 4];
                    lstm_epi(f, bias1, c1s, &hst[par ^ 1][0][0][0], R0, kq, c, ub0);
                }
                if (s >= 1) {
                    f32x4 f = ownB + *(const f32x4*)&xb[par ^ 1][1][p][kh ^ 1][lane * 4];
                    lstm_epi(f, bias2, c2s, &hst[par ^ 1][1][0][0], R0, kq, c, ub0);
                }
            }

            // (4) MFMA partials chunk ch (half-K, 2 tiles; each A feeds 2 MFMAs)
            if (ch <= 7) {
                const char* q1b = (const char*)&Q1[par][0] + c * (QS * 2);
                const char* q2b = (const char*)&Q2[par][0] + c * (QS * 2);
                if (notLast) {   // L1: kh0 = h1[0:288]; kh1 = h1[288:512] + x
                    f32x4 a0{0.f, 0.f, 0.f, 0.f}, a1 = a0;
                    if (kh == 0) {
#pragma unroll
                        for (int kc = 0; kc < 9; ++kc) {
                            f16x8 av = *(const f16x8*)(q1b + kc * 64 + kq * 16);
                            MFMA16(av, w1f[0][kc], a0); MFMA16(av, w1f[1][kc], a1);
                        }
                    } else {
#pragma unroll
                        for (int kc = 0; kc < 7; ++kc) {
                            f16x8 av = *(const f16x8*)(q1b + (kc + 9) * 64 + kq * 16);
                            MFMA16(av, w1f[0][kc], a0); MFMA16(av, w1f[1][kc], a1);
                        }
                        {
                            f16x8 av = *(const f16x8*)&Xp[par][c][kq * 8];
                            MFMA16(av, w1f[0][7], a0); MFMA16(av, w1f[1][7], a1);
                            av = *(const f16x8*)&Xp[par][c][32 + kq * 8];
                            MFMA16(av, w1f[0][8], a0); MFMA16(av, w1f[1][8], a1);
                        }
                    }
                    f32x4 mine   = (kh == 0) ? a0 : a1;
                    f32x4 theirs = (kh == 0) ? a1 : a0;
                    *(f32x4*)&xb[par][0][p][kh][lane * 4] = theirs;
                    ownA = mine;
                }
                if (s >= 1) {    // L2: kh0 = h2 (Q2); kh1 = h1 (Q1)
                    const char* qb = kh ? q1b : q2b;
                    f32x4 b0{0.f, 0.f, 0.f, 0.f}, b1 = b0;
#pragma unroll
                    for (int kc = 0; kc < 16; ++kc) {
                        f16x8 av = *(const f16x8*)(qb + kc * 64 + kq * 16);
                        MFMA16(av, w2f[0][kc], b0); MFMA16(av, w2f[1][kc], b1);
                    }
                    f32x4 mine   = (kh == 0) ? b0 : b1;
                    f32x4 theirs = (kh == 0) ? b1 : b0;
                    *(f32x4*)&xb[par][1][p][kh][lane * 4] = theirs;
                    ownB = mine;
                }
            }

            // (5) x(ch+1) -> Xp[par^1]
            if (havex)
                *(f16x2*)&Xp[par ^ 1][xrow][xc2] =
                    (f16x2){(_Float16)xnext.x, (_Float16)xnext.y};

            __syncthreads();   // single barrier per region
        }

        // ---- tail: hstore chunk 7 (epi'd in region 8 -> hst[1]) ----
        if (tid < 256) {
            int layer = tid >> 7, r = (tid >> 3) & 15, cq = tid & 7;
            f16x4 hv = *(const f16x4*)&hst[1][layer][r][cq * 4];
            _Float16* dst = (layer ? h2w : h1w)
                + (size_t)(r0 + 112 + r) * HH + cg * 32 + cq * 4;
            *(f16x4*)dst = hv;
        }
        __syncthreads();

        // ---- rowgroup barrier, relaxed (validated r9) ----
        if (tid == 0) {
            __hip_atomic_fetch_add(&bar[rg * 32], 1u,
                                   __ATOMIC_RELAXED, __HIP_MEMORY_SCOPE_AGENT);
            const unsigned target = 16u * (unsigned)(s + 1);
            while (__hip_atomic_load(&bar[rg * 32],
                                     __ATOMIC_RELAXED, __HIP_MEMORY_SCOPE_AGENT) < target)
                __builtin_amdgcn_s_sleep(2);
        }
        __syncthreads();
    }

    // ---- dense head: out = h2_127 @ Wd + bd (cg==0 blocks; 4 threads/row) ----
    if (cg == 0) {
        const _Float16* hf = h2b + (size_t)((TT + 1) & 1) * 2048 * HH;
        int row = tid >> 2, part = tid & 3;
        const _Float16* hr = hf + (size_t)(r0 + row) * HH + part * 128;
        const float* wd = Wd + part * 128;
        float ssum = 0.f;
#pragma unroll
        for (int u8 = 0; u8 < 16; ++u8) {
            f16x8 hv = *(const f16x8*)(hr + u8 * 8);
#pragma unroll
            for (int k = 0; k < 8; ++k) ssum += (float)hv[k] * wd[u8 * 8 + k];
        }
        ssum += __shfl_xor(ssum, 1);
        ssum += __shfl_xor(ssum, 2);
        if (part == 0) out[r0 + row] = ssum + bd[0];
    }
}

extern "C" void kernel_launch(void* const* d_in, const int* in_sizes, int n_in,
                              void* d_out, int out_size, void* d_ws, size_t ws_size,
                              hipStream_t stream)
{
    const float* x  = (const float*)d_in[0];
    const float* W1 = (const float*)d_in[1];
    const float* U1 = (const float*)d_in[2];
    const float* b1 = (const float*)d_in[3];
    const float* W2 = (const float*)d_in[4];
    const float* U2 = (const float*)d_in[5];
    const float* b2 = (const float*)d_in[6];
    const float* Wd = (const float*)d_in[7];
    const float* bd = (const float*)d_in[8];
    float* out = (float*)d_out;

    char* ws = (char*)d_ws;
    size_t off = 0;
    _Float16* Bp1 = (_Float16*)(ws + off); off += (size_t)K1 * GG * 2;
    _Float16* Bp2 = (_Float16*)(ws + off); off += (size_t)K2 * GG * 2;
    float*    pb1 = (float*)(ws + off);    off += (size_t)GG * 4;
    float*    pb2 = (float*)(ws + off);    off += (size_t)GG * 4;
    _Float16* h1b = (_Float16*)(ws + off); off += (size_t)2 * 2048 * HH * 2;
    _Float16* h2b = (_Float16*)(ws + off); off += (size_t)2 * 2048 * HH * 2;
    unsigned* bar = (unsigned*)(ws + off); off += 16 * 32 * 4;

    hipMemsetAsync(h1b, 0, (size_t)2 * 2048 * HH * 2, stream);
    hipMemsetAsync(h2b, 0, (size_t)2 * 2048 * HH * 2, stream);
    hipMemsetAsync(bar, 0, 16 * 32 * 4, stream);

    pack_weights<<<KB1, 256, 0, stream>>>(U1, W1, b1, KB1, HH, Bp1, pb1);
    pack_weights<<<KB2, 256, 0, stream>>>(U2, W2, b2, KB2, HH, Bp2, pb2);
    lstm_persist<<<NBLK, 512, 0, stream>>>(x, Bp1, pb1, Bp2, pb2, Wd, bd,
                                           h1b, h2b, bar, out);
}